// Round 11
// baseline (284.195 us; speedup 1.0000x reference)
//
#include <hip/hip_runtime.h>

// ---------------------------------------------------------------------------
// SelfCrossAttention: B=4, T=1024+1024, d=512, H=8, hd=64. fp32 I/O,
// bf16 MFMA internals.
// NEW (R11): per-batch TIME SORT of all 2048 positions -> mask becomes
// (block-)causal in sorted order -> attn skips fully-masked 32-key windows
// (~47% of all windows). Softmax is permutation-invariant over keys; output
// rows are un-permuted at the final y write. qkv scatters q/k/v into sorted
// rows (pays scatter once at store; attn hot-loop loads stay contiguous).
// prep (X->bf16; W->wt[n][k] bf16 q-scaled 0.125*log2e; W_proj->wtp;
//       + 4 blocks: bitonic sort -> st/perm/inv per batch)
//   -> qkv (128x128 glds GEMM; q/k operand-swapped b64 stores to sorted
//           rows; V scattered to sorted+window-permuted [bh][j][t'])
//   -> attn (S^T flash, 64q/wave, interleaved 4-way key split, exp2 softmax,
//            l via ones-A MFMA, per-window causal skip; natural VGPR — never
//            cap: R9's launch_bounds(256,4) spilled accumulators, 5x loss)
//   -> proj (glds GEMM, operand-swapped dwordx4 stores, tuple split).
// ---------------------------------------------------------------------------

typedef short     bf16x8 __attribute__((ext_vector_type(8)));
typedef short     bf16x4 __attribute__((ext_vector_type(4)));
typedef float     f32x4  __attribute__((ext_vector_type(4)));
typedef int       i32x4  __attribute__((ext_vector_type(4)));

#define DI __device__ __forceinline__

DI unsigned short f2b(float f) {            // fp32 -> bf16 bits, RNE-ish
    union { float f; unsigned int u; } x; x.f = f;
    unsigned int r = x.u + 0x7fffu + ((x.u >> 16) & 1u);
    return (unsigned short)(r >> 16);
}
DI unsigned int fbits(float f) { union { float f; unsigned int u; } x; x.f = f; return x.u; }
DI float bitsf(unsigned int u) { union { unsigned int u; float f; } x; x.u = u; return x.f; }
DI float b2f(unsigned short v) { return bitsf(((unsigned int)v) << 16); }

DI void glds16(const unsigned short* g, unsigned short* l) {   // 16B global->LDS
    __builtin_amdgcn_global_load_lds(
        (const __attribute__((address_space(1))) void*)g,
        (__attribute__((address_space(3))) void*)l, 16, 0, 0);
}

#define QSCALE 0.18033688011112042f   // 0.125 * log2(e): exp2-domain scores

// window permutation of a sorted position s (arbitrary, not 4-aligned):
// B-slot quad*8+j <-> keys {4q..4q+3} u {16+4q..16+4q+3} inside each 32-window
DI int wperm(int s) {
    int r = s & 31;
    int p = (r < 16) ? (((r >> 2) << 3) | (r & 3))
                     : ((((r - 16) >> 2) << 3) + 4 + (r & 3));
    return (s & ~31) + p;
}

// ---------------------------------------------------------------------------
// prep: [0,2048): X fp32 -> bf16 flat.
//       [2048,2432): W_self/W_cross -> wt[src][n][k], q-section * QSCALE
//       [2432,2496): W_proj -> wtp[n][k]
//       [2496,2500): per-batch bitonic time sort -> st/perm/inv
// ---------------------------------------------------------------------------
__global__ __launch_bounds__(256)
void prep_kernel(const float* __restrict__ Xs, const float* __restrict__ Xc,
                 const float* __restrict__ Ws, const float* __restrict__ Wc,
                 const float* __restrict__ Wp,
                 const int* __restrict__ t_self, const int* __restrict__ t_cross,
                 unsigned short* __restrict__ xb, unsigned short* __restrict__ wt,
                 unsigned short* __restrict__ wtp,
                 int* __restrict__ st, int* __restrict__ perm, int* __restrict__ inv)
{
    const int bid = blockIdx.x, tid = threadIdx.x;
    if (bid < 2048) {
        int idx = bid * 2048 + tid * 8;
        const float* s = (idx < 2097152) ? (Xs + idx) : (Xc + idx - 2097152);
        f32x4 a0 = *(const f32x4*)s;
        f32x4 a1 = *(const f32x4*)(s + 4);
        bf16x8 v;
#pragma unroll
        for (int j = 0; j < 4; ++j) {
            ((unsigned short*)&v)[j]     = f2b(a0[j]);
            ((unsigned short*)&v)[4 + j] = f2b(a1[j]);
        }
        *(bf16x8*)(xb + idx) = v;
        return;
    }
    if (bid >= 2496) {                       // bitonic sort: key = time<<11 | idx
        __shared__ unsigned int S[2048];
        int b = bid - 2496;
        for (int i = tid; i < 2048; i += 256) {
            int t = (i < 1024) ? t_self[b * 1024 + i] : t_cross[b * 1024 + i - 1024];
            S[i] = (((unsigned int)t) << 11) | (unsigned int)i;
        }
        for (unsigned int k = 2; k <= 2048; k <<= 1)
            for (unsigned int j = k >> 1; j > 0; j >>= 1) {
                __syncthreads();
                for (int x = tid; x < 2048; x += 256) {
                    int p = x ^ (int)j;
                    if (p > x) {
                        unsigned int a = S[x], c = S[p];
                        bool up = ((x & k) == 0);
                        if ((a > c) == up) { S[x] = c; S[p] = a; }
                    }
                }
            }
        __syncthreads();
        for (int i = tid; i < 2048; i += 256) {
            unsigned int v = S[i];
            int o = (int)(v & 2047u);
            st[b * 2048 + i]   = (int)(v >> 11);
            perm[b * 2048 + i] = o;
            inv[b * 2048 + o]  = i;
        }
        return;
    }
    __shared__ unsigned short Tt[64 * 72];
    const float* W;
    unsigned short* dst;
    int k0, n0, ldn;
    float sc = 1.0f;
    if (bid < 2432) {
        int tj  = bid - 2048;
        int src = tj >= 192;  tj -= src * 192;
        k0  = (tj / 24) * 64;
        n0  = (tj % 24) * 64;
        W   = src ? Wc : Ws;
        ldn = 1536;
        dst = wt + (size_t)src * 786432;
        if (n0 < 512) sc = QSCALE;
    } else {
        int tj = bid - 2432;
        k0  = (tj >> 3) * 64;
        n0  = (tj & 7) * 64;
        W   = Wp;
        ldn = 512;
        dst = wtp;
    }
#pragma unroll
    for (int r = 0; r < 4; ++r) {
        int g  = tid + r * 256;
        int kr = g >> 4, nc4 = (g & 15) * 4;
        f32x4 v = *(const f32x4*)(W + (size_t)(k0 + kr) * ldn + n0 + nc4);
#pragma unroll
        for (int u = 0; u < 4; ++u)
            Tt[(nc4 + u) * 72 + kr] = f2b(v[u] * sc);
    }
    __syncthreads();
#pragma unroll
    for (int r = 0; r < 2; ++r) {
        int c = tid + r * 256;
        int nl = c >> 3, k8 = (c & 7) * 8;
        *(bf16x8*)(dst + (size_t)(n0 + nl) * 512 + k0 + k8) =
            *(const bf16x8*)(Tt + nl * 72 + k8);
    }
}

// ---------------------------------------------------------------------------
// QKV: xb @ wt^T + bias. 128x128 tile, glds staging. q/k operand-swapped
// (C=[n][t], b64 stores) scattered to SORTED rows via inv; V original
// orientation, scattered per-element to sorted+window-permuted positions.
// ---------------------------------------------------------------------------
__global__ __launch_bounds__(256)
void qkv_kernel(const unsigned short* __restrict__ xb,
                const unsigned short* __restrict__ wt,
                const float* __restrict__ bs, const float* __restrict__ bc,
                const int* __restrict__ inv,
                unsigned short* __restrict__ qb, unsigned short* __restrict__ kb,
                unsigned short* __restrict__ vtb)
{
    const int src = blockIdx.z;
    const int m0 = blockIdx.x * 128, n0 = blockIdx.y * 128;
    const float* bias = src ? bc : bs;
    const unsigned short* X = xb + (size_t)src * 2097152;
    const unsigned short* W = wt + (size_t)src * 786432;

    __shared__ unsigned short As[128 * 32];
    __shared__ unsigned short Bs[128 * 32];

    const int tid = threadIdx.x, lane = tid & 63, w = tid >> 6;
    const int quad = lane >> 4, r16 = lane & 15;
    const int mrow = (w >> 1) * 64, ncol = (w & 1) * 64;
    const bool qk = (n0 < 1024);

    const f32x4 fz = {0.f, 0.f, 0.f, 0.f};
    f32x4 acc[4][4];
#pragma unroll
    for (int a = 0; a < 4; ++a)
#pragma unroll
        for (int b = 0; b < 4; ++b) acc[a][b] = fz;

    const int ci   = w << 1;
    const int rofs = lane >> 2, kofs = (lane & 3) * 8;
    const unsigned short* gA = X + (size_t)(m0 + ci * 16 + rofs) * 512 + kofs;
    const unsigned short* gB = W + (size_t)(n0 + ci * 16 + rofs) * 512 + kofs;
    unsigned short* lA = As + ci * 512 + lane * 8;
    unsigned short* lB = Bs + ci * 512 + lane * 8;

    for (int k0 = 0; k0 < 512; k0 += 32) {
        glds16(gA + k0, lA);
        glds16(gA + 16 * 512 + k0, lA + 512);
        glds16(gB + k0, lB);
        glds16(gB + 16 * 512 + k0, lB + 512);
        __syncthreads();

        bf16x8 af[4], bfr[4];
#pragma unroll
        for (int ms = 0; ms < 4; ++ms)
            af[ms] = *(const bf16x8*)(As + (mrow + ms * 16 + r16) * 32 + quad * 8);
#pragma unroll
        for (int ns = 0; ns < 4; ++ns)
            bfr[ns] = *(const bf16x8*)(Bs + (ncol + ns * 16 + r16) * 32 + quad * 8);
        if (qk) {
#pragma unroll
            for (int a = 0; a < 4; ++a)
#pragma unroll
                for (int b = 0; b < 4; ++b)
                    acc[a][b] = __builtin_amdgcn_mfma_f32_16x16x32_bf16(
                        bfr[a], af[b], acc[a][b], 0, 0, 0);   // C = [n][t]
        } else {
#pragma unroll
            for (int a = 0; a < 4; ++a)
#pragma unroll
                for (int b = 0; b < 4; ++b)
                    acc[a][b] = __builtin_amdgcn_mfma_f32_16x16x32_bf16(
                        af[a], bfr[b], acc[a][b], 0, 0, 0);   // C = [t][n]
        }
        __syncthreads();
    }

    const int bi0 = m0 >> 10;                 // block-uniform batch index
    const int* invb = inv + bi0 * 2048;

    if (qk) {
        const bool isq = (n0 < 512);
        unsigned short* dst = isq ? qb : kb;
        const float bsc = isq ? QSCALE : 1.0f;
#pragma unroll
        for (int ws = 0; ws < 4; ++ws) {
            int nb = n0 + ncol + ws * 16 + quad * 4;      // 4 consecutive n
            f32x4 bb = *(const f32x4*)(bias + nb);
            int col = nb & 511, hh = col >> 6, j0 = col & 63;
#pragma unroll
            for (int xs = 0; xs < 4; ++xs) {
                int mb = m0 + mrow + xs * 16 + r16;
                int tg = (mb & 1023) + (src << 10);
                int sp = invb[tg];                         // sorted row
                bf16x4 pk;
#pragma unroll
                for (int i = 0; i < 4; ++i)
                    pk[i] = (short)f2b(acc[ws][xs][i] + bb[i] * bsc);
                *(bf16x4*)(dst + (((size_t)(bi0 * 8 + hh) * 2048 + sp) << 6) + j0) = pk;
            }
        }
    } else {
#pragma unroll
        for (int ms = 0; ms < 4; ++ms)
#pragma unroll
            for (int ns = 0; ns < 4; ++ns) {
                int n = n0 + ncol + ns * 16 + r16;
                int col = n & 511, hh = col >> 6, j = col & 63;
                float bb = bias[n];
                int mb = m0 + mrow + ms * 16 + quad * 4;
                int tg0 = (mb & 1023) + (src << 10);
                i32x4 sp4 = *(const i32x4*)(invb + tg0);   // 4 sorted rows
                unsigned short* vrow = vtb + (((size_t)(bi0 * 8 + hh) * 64 + j) << 11);
#pragma unroll
                for (int i = 0; i < 4; ++i)
                    vrow[wperm(sp4[i])] = f2b(acc[ms][ns][i] + bb);
            }
    }
}

// ---------------------------------------------------------------------------
// attn: S^T flash in SORTED order, exp2 domain. Block 256 thr = 4 waves;
// block = 64 sorted queries of one bh; wave covers all 64 q x 8 interleaved
// K-tiles (kt = it*4 + ksplit for balance). Per 32-key window: skip if
// st[kw] > st[q0+63] (fully masked — block-causal); else two S-tiles ->
// exp2 -> perm-pack -> K=32 PV; l via ones-A MFMA. Final y write scatters
// to ORIGINAL rows via perm. Grid swizzled: each XCD sees 4 bh.
// ---------------------------------------------------------------------------
__global__ __launch_bounds__(256)
void attn_kernel(const unsigned short* __restrict__ qb,
                 const unsigned short* __restrict__ kb,
                 const unsigned short* __restrict__ vt,
                 const int* __restrict__ st, const int* __restrict__ perm,
                 unsigned short* __restrict__ y)
{
    const int bid = blockIdx.x;
    const int bh = ((bid & 7) << 2) | ((bid >> 3) & 3);   // XCD-local bh group
    const int qt = bid >> 5;
    const int b = bh >> 3, h = bh & 7;
    const int tid = threadIdx.x, ksplit = tid >> 6, lane = tid & 63;
    const int quad = lane >> 4, r16 = lane & 15;

    const unsigned short* Q = qb + (size_t)bh * 131072;
    const unsigned short* K = kb + (size_t)bh * 131072;
    const unsigned short* V = vt + (size_t)bh * 131072;
    const int* stb  = st + b * 2048;
    const int* prmb = perm + b * 2048;

    __shared__ unsigned short Op[4][64 * 68];   // bf16 partial O^T per split
    __shared__ float Ls[4][64];

    const int q0 = qt * 64;
    const int qmax = stb[q0 + 63];              // sorted: tile max time

    bf16x8 qf[4][2];
#pragma unroll
    for (int g = 0; g < 4; ++g)
#pragma unroll
        for (int ks = 0; ks < 2; ++ks)
            qf[g][ks] = *(const bf16x8*)(Q + (size_t)(q0 + g * 16 + r16) * 64
                                           + ks * 32 + quad * 8);

    int tq[4];
#pragma unroll
    for (int g = 0; g < 4; ++g) tq[g] = stb[q0 + g * 16 + r16];

    const f32x4 fz = {0.f, 0.f, 0.f, 0.f};
    f32x4 ot[4][4], al[4];
#pragma unroll
    for (int g = 0; g < 4; ++g) {
        al[g] = fz;
#pragma unroll
        for (int nt = 0; nt < 4; ++nt) ot[g][nt] = fz;
    }
    const bf16x8 ones = {(short)0x3F80, (short)0x3F80, (short)0x3F80, (short)0x3F80,
                         (short)0x3F80, (short)0x3F80, (short)0x3F80, (short)0x3F80};

    for (int it = 0; it < 8; ++it) {
        const int kt = it * 4 + ksplit;         // interleaved key split
        const int krow = kt * 64;

#pragma unroll
        for (int c = 0; c < 2; ++c) {           // 32-key windows
            const int kw = krow + c * 32;
            if (stb[kw] > qmax) continue;       // fully masked window: skip all

            i32x4 tk0 = *(const i32x4*)(stb + kw + quad * 4);
            i32x4 tk1 = *(const i32x4*)(stb + kw + 16 + quad * 4);
            const unsigned short* kr0 = K + (size_t)(kw + r16) * 64 + quad * 8;
            const unsigned short* kr1 = K + (size_t)(kw + 16 + r16) * 64 + quad * 8;
            bf16x8 ka00 = *(const bf16x8*)(kr0);
            bf16x8 ka01 = *(const bf16x8*)(kr0 + 32);
            bf16x8 ka10 = *(const bf16x8*)(kr1);
            bf16x8 ka11 = *(const bf16x8*)(kr1 + 32);

            bf16x8 pf[4];
#pragma unroll
            for (int g = 0; g < 4; ++g) {
                f32x4 s0 = fz, s1 = fz;
                s0 = __builtin_amdgcn_mfma_f32_16x16x32_bf16(ka00, qf[g][0], s0, 0, 0, 0);
                s0 = __builtin_amdgcn_mfma_f32_16x16x32_bf16(ka01, qf[g][1], s0, 0, 0, 0);
                s1 = __builtin_amdgcn_mfma_f32_16x16x32_bf16(ka10, qf[g][0], s1, 0, 0, 0);
                s1 = __builtin_amdgcn_mfma_f32_16x16x32_bf16(ka11, qf[g][1], s1, 0, 0, 0);
                float e[8];
#pragma unroll
                for (int i = 0; i < 4; ++i) {
                    float a0 = (tq[g] >= tk0[i]) ? s0[i] : -1e9f;   // select ARG
                    float a1 = (tq[g] >= tk1[i]) ? s1[i] : -1e9f;
                    e[i]     = __builtin_amdgcn_exp2f(a0);          // exp2 domain
                    e[4 + i] = __builtin_amdgcn_exp2f(a1);
                }
                union { unsigned int d[4]; bf16x8 v; } pu;          // truncate-pack
                pu.d[0] = __builtin_amdgcn_perm(fbits(e[1]), fbits(e[0]), 0x07060302u);
                pu.d[1] = __builtin_amdgcn_perm(fbits(e[3]), fbits(e[2]), 0x07060302u);
                pu.d[2] = __builtin_amdgcn_perm(fbits(e[5]), fbits(e[4]), 0x07060302u);
                pu.d[3] = __builtin_amdgcn_perm(fbits(e[7]), fbits(e[6]), 0x07060302u);
                pf[g] = pu.v;
                // l partial from the SAME stored-precision P (ones-A MFMA)
                al[g] = __builtin_amdgcn_mfma_f32_16x16x32_bf16(ones, pf[g], al[g], 0, 0, 0);
            }

            // O^T += V^T · P^T  (K=32, b128 V loads from permuted layout)
#pragma unroll
            for (int nt = 0; nt < 4; ++nt) {
                bf16x8 va = *(const bf16x8*)(V + (size_t)(nt * 16 + r16) * 2048
                                               + kw + quad * 8);
                ot[0][nt] = __builtin_amdgcn_mfma_f32_16x16x32_bf16(va, pf[0], ot[0][nt], 0, 0, 0);
                ot[1][nt] = __builtin_amdgcn_mfma_f32_16x16x32_bf16(va, pf[1], ot[1][nt], 0, 0, 0);
                ot[2][nt] = __builtin_amdgcn_mfma_f32_16x16x32_bf16(va, pf[2], ot[2][nt], 0, 0, 0);
                ot[3][nt] = __builtin_amdgcn_mfma_f32_16x16x32_bf16(va, pf[3], ot[3][nt], 0, 0, 0);
            }
        }
    }

    // write partials (bf16 O^T, fp32 l) and merge
    unsigned short* opw = Op[ksplit];
#pragma unroll
    for (int g = 0; g < 4; ++g)
#pragma unroll
        for (int nt = 0; nt < 4; ++nt) {
            union { unsigned int u[2]; bf16x4 v; } pk;
            pk.u[0] = (unsigned int)f2b(ot[g][nt][0]) | ((unsigned int)f2b(ot[g][nt][1]) << 16);
            pk.u[1] = (unsigned int)f2b(ot[g][nt][2]) | ((unsigned int)f2b(ot[g][nt][3]) << 16);
            *(bf16x4*)(opw + (g * 16 + r16) * 68 + nt * 16 + quad * 4) = pk.v;
        }
    if (quad == 0) {
#pragma unroll
        for (int g = 0; g < 4; ++g) Ls[ksplit][g * 16 + r16] = al[g][0];
    }
    __syncthreads();

    for (int c = tid; c < 1024; c += 256) {
        int q = c >> 4, j4 = (c & 15) * 4;
        float l = Ls[0][q] + Ls[1][q] + Ls[2][q] + Ls[3][q];
        float inv = (l > 0.f) ? (1.f / l) : 0.f;
        float s[4] = {0.f, 0.f, 0.f, 0.f};
#pragma unroll
        for (int sp = 0; sp < 4; ++sp) {
            bf16x4 v = *(const bf16x4*)(Op[sp] + q * 68 + j4);
#pragma unroll
            for (int i = 0; i < 4; ++i)
                s[i] += b2f(((const unsigned short*)&v)[i]);
        }
        bf16x4 pk;
#pragma unroll
        for (int i = 0; i < 4; ++i) pk[i] = (short)f2b(s[i] * inv);
        int pr = prmb[q0 + q];                  // un-permute to original row
        *(bf16x4*)(y + (((size_t)(b * 2048 + pr)) << 9) + h * 64 + j4) = pk;
    }
}

// ---------------------------------------------------------------------------
// proj: Y(8192x512 bf16) @ wtp^T + b -> fp32 out (tuple split). Operand-
// swapped MFMA -> each lane holds 4 consecutive n at one t -> dwordx4 stores.
// ---------------------------------------------------------------------------
__global__ __launch_bounds__(256)
void proj_kernel(const unsigned short* __restrict__ X,
                 const unsigned short* __restrict__ Wt,
                 const float* __restrict__ bias,
                 float* __restrict__ out)
{
    const int m0 = blockIdx.x * 128, n0 = blockIdx.y * 128;
    __shared__ unsigned short As[128 * 32];
    __shared__ unsigned short Bs[128 * 32];

    const int tid = threadIdx.x, lane = tid & 63, w = tid >> 6;
    const int quad = lane >> 4, r16 = lane & 15;
    const int mrow = (w >> 1) * 64, ncol = (w & 1) * 64;

    const f32x4 fz = {0.f, 0.f, 0.f, 0.f};
    f32x4 acc[4][4];
#pragma unroll
    for (int a = 0; a < 4; ++a)
#pragma unroll
        for (int b = 0; b < 4; ++b) acc[a][b] = fz;

    const int ci   = w << 1;
    const int rofs = lane >> 2, kofs = (lane & 3) * 8;
    const unsigned short* gA = X + (size_t)(m0 + ci * 16 + rofs) * 512 + kofs;
    const unsigned short* gB = Wt + (size_t)(n0 + ci * 16 + rofs) * 512 + kofs;
    unsigned short* lA = As + ci * 512 + lane * 8;
    unsigned short* lB = Bs + ci * 512 + lane * 8;

    for (int k0 = 0; k0 < 512; k0 += 32) {
        glds16(gA + k0, lA);
        glds16(gA + 16 * 512 + k0, lA + 512);
        glds16(gB + k0, lB);
        glds16(gB + 16 * 512 + k0, lB + 512);
        __syncthreads();

        bf16x8 af[4], bfr[4];
#pragma unroll
        for (int ms = 0; ms < 4; ++ms)
            af[ms] = *(const bf16x8*)(As + (mrow + ms * 16 + r16) * 32 + quad * 8);
#pragma unroll
        for (int ns = 0; ns < 4; ++ns)
            bfr[ns] = *(const bf16x8*)(Bs + (ncol + ns * 16 + r16) * 32 + quad * 8);
#pragma unroll
        for (int a = 0; a < 4; ++a)
#pragma unroll
            for (int b = 0; b < 4; ++b)
                acc[a][b] = __builtin_amdgcn_mfma_f32_16x16x32_bf16(
                    bfr[a], af[b], acc[a][b], 0, 0, 0);       // C = [n][t]
        __syncthreads();
    }

#pragma unroll
    for (int ws = 0; ws < 4; ++ws) {
        int nb = n0 + ncol + ws * 16 + quad * 4;
        f32x4 bb = *(const f32x4*)(bias + nb);
#pragma unroll
        for (int xs = 0; xs < 4; ++xs) {
            int m = m0 + mrow + xs * 16 + r16;
            int bi = m >> 11, t = m & 2047;
            f32x4 v;
#pragma unroll
            for (int i = 0; i < 4; ++i) v[i] = acc[ws][xs][i] + bb[i];
            size_t idx = (t < 1024)
                ? ((size_t)bi * 1024 + t) * 512 + nb
                : (size_t)2097152 + ((size_t)bi * 1024 + (t - 1024)) * 512 + nb;
            *(f32x4*)(out + idx) = v;
        }
    }
}

// ---------------------------------------------------------------------------
extern "C" void kernel_launch(void* const* d_in, const int* in_sizes, int n_in,
                              void* d_out, int out_size, void* d_ws, size_t ws_size,
                              hipStream_t stream)
{
    const float* self_seq  = (const float*)d_in[0];
    const float* cross_seq = (const float*)d_in[1];
    const int*   t_self    = (const int*)d_in[2];
    const int*   t_cross   = (const int*)d_in[3];
    const float* W_self    = (const float*)d_in[4];
    const float* b_self    = (const float*)d_in[5];
    const float* W_cross   = (const float*)d_in[6];
    const float* b_cross   = (const float*)d_in[7];
    const float* W_proj    = (const float*)d_in[8];
    const float* b_proj    = (const float*)d_in[9];
    float* out = (float*)d_out;

    // ws (32 MB): q, k, vt, y. d_out slack holds xb/wt/wtp + sort arrays
    // (st/perm/inv, 96 KB) until proj overwrites everything at the end.
    unsigned short* qbuf = (unsigned short*)d_ws;
    unsigned short* kbuf = qbuf + 4194304;
    unsigned short* vtb  = kbuf + 4194304;
    unsigned short* ybuf = vtb + 4194304;
    unsigned short* xb   = (unsigned short*)d_out;
    unsigned short* wt   = xb + 4194304;
    unsigned short* wtp  = wt + 1572864;
    int* stb  = (int*)(wtp + 262144);
    int* prmb = stb + 8192;
    int* invb = prmb + 8192;

    prep_kernel<<<dim3(2500), 256, 0, stream>>>(
        self_seq, cross_seq, W_self, W_cross, W_proj, t_self, t_cross,
        xb, wt, wtp, stb, prmb, invb);

    qkv_kernel<<<dim3(32, 12, 2), 256, 0, stream>>>(
        xb, wt, b_self, b_cross, invb, qbuf, kbuf, vtb);

    attn_kernel<<<dim3(1024), 256, 0, stream>>>(
        qbuf, kbuf, vtb, stb, prmb, ybuf);

    proj_kernel<<<dim3(64, 4), 256, 0, stream>>>(
        ybuf, wtp, b_proj, out);
}